// Round 4
// baseline (195.189 us; speedup 1.0000x reference)
//
#include <hip/hip_runtime.h>

#define TF 512
#define VF 512
#define BB 4
#define ST 32
#define SV 64
#define HW 196
#define NBV (BB * SV)       // 256 (b,v) pairs
#define NSEG 7              // h-segments per (b,v) -> 7 blocks/CU, SEGH=28 = 7 rows/wave exact
#define SEGH (HW / NSEG)    // 28
#define NDP (SV * NSEG)     // 448 denom partials per b

// Math: softmax over (v,h) is invariant to the additive per-(b,t) text score,
// so weights are t-independent and out[b,s,v,f] = G[b,v,f]/denom[b] for all 32 s.
//
// R3 results: warm phase-A = 4.55 us/pass (22 TB/s!) and launch gaps ~0.
// So controllable 47 us = coldA + phaseB; either coldA ~40 (cold read at
// 2.6 TB/s -> fill-writeback contention, structural) or coldA ~16 and
// phaseB ~25 (4x over model -> 128KB-stride store aliasing suspect).
// These demand opposite actions -> R4 measures coldA directly.
//
// R4 = FINAL INSTRUMENTATION ROUND. The 12-pass probe runs FIRST, i.e. in
// exactly production-A's post-fill cold slot: dur = coldA + 11*4.55 >= 66 us
// whenever coldA >= 16 -> guaranteed top-5 row with FETCH_SIZE. Production
// phase A then runs L3-warm (probe pre-warmed video); probe's 12x-scaled
// Gpart/dpart are overwritten by production A before out_kernel reads them
// (same-stream ordering) -> output unchanged.
//
// Pre-committed R5 decision (coldA = probe_row_dur - 50):
//   row ~66-75, FETCH ~103MB -> coldA near HBM floor; phaseB ~20+ is the
//                               target: contiguous out-writes, kill 128KB
//                               stride replication.
//   row >= 85, FETCH ~103MB  -> coldA ~40 at 2.6 TB/s despite 22 TB/s warm
//                               capability: fill-drain contention, structural
//                               -> revert to R2, declare ROOFLINE.
//   row absent                -> video never evicted, coldA small -> phaseB
//                               is the whole gap -> same as first row.

template <int PASSES>
__global__ __launch_bounds__(256) void score_acc_kernel(const float4* __restrict__ video,
                                                        const float* __restrict__ w,
                                                        float4* __restrict__ Gpart,
                                                        float* __restrict__ dpart) {
    int seg  = blockIdx.x;          // 0..6
    int bv   = blockIdx.y;          // 0..255
    int tid  = threadIdx.x;
    int wave = tid >> 6;
    int lane = tid & 63;

    const float4* wv4 = (const float4*)(w + TF);
    float4 w0 = wv4[lane];
    float4 w1 = wv4[lane + 64];

    const float4* vbase = video + ((size_t)bv * HW + seg * SEGH + wave) * (VF / 4);

    float4 acc0 = make_float4(0.f, 0.f, 0.f, 0.f);
    float4 acc1 = make_float4(0.f, 0.f, 0.f, 0.f);
    float  esum = 0.f;

    // Accumulate across passes (no reset) so every pass's loads/exp feed the
    // final write -> compiler cannot dead-code redundant passes (rule #17).
    // PASSES=1 is the production kernel, identical math to R2.
    #pragma unroll 1
    for (int p = 0; p < PASSES; ++p) {
        const float4* row = vbase;
        float4 x0 = row[lane];
        float4 x1 = row[lane + 64];

        #pragma unroll
        for (int it = 0; it < SEGH / 4; ++it) {       // 7 iterations, rows wave,wave+4,...
            const float4* nrow = row + 4 * (VF / 4);
            float4 n0 = x0, n1 = x1;                  // dead copies on last iter (DCE'd)
            if (it < SEGH / 4 - 1) {                  // prefetch next row before the
                n0 = nrow[lane];                      // serial shuffle chain
                n1 = nrow[lane + 64];
            }
            float s = x0.x * w0.x + x0.y * w0.y + x0.z * w0.z + x0.w * w0.w
                    + x1.x * w1.x + x1.y * w1.y + x1.z * w1.z + x1.w * w1.w;
            #pragma unroll
            for (int off = 32; off > 0; off >>= 1)
                s += __shfl_xor(s, off, 64);
            float e = __expf(s);
            esum += e;                                // identical across lanes
            acc0.x = fmaf(e, x0.x, acc0.x);
            acc0.y = fmaf(e, x0.y, acc0.y);
            acc0.z = fmaf(e, x0.z, acc0.z);
            acc0.w = fmaf(e, x0.w, acc0.w);
            acc1.x = fmaf(e, x1.x, acc1.x);
            acc1.y = fmaf(e, x1.y, acc1.y);
            acc1.z = fmaf(e, x1.z, acc1.z);
            acc1.w = fmaf(e, x1.w, acc1.w);
            x0 = n0; x1 = n1; row = nrow;
        }
    }

    __shared__ float4 sacc[4][VF / 4];
    __shared__ float  sd[4];
    sacc[wave][lane]      = acc0;
    sacc[wave][lane + 64] = acc1;
    if (lane == 0) sd[wave] = esum;
    __syncthreads();

    int c = tid & 127, half = tid >> 7;
    float4 a  = sacc[half * 2][c];
    float4 bq = sacc[half * 2 + 1][c];
    float4 t  = make_float4(a.x + bq.x, a.y + bq.y, a.z + bq.z, a.w + bq.w);
    sacc[half * 2][c] = t;
    __syncthreads();
    if (half == 0) {
        float4 u = sacc[2][c];
        Gpart[((size_t)seg * NBV + bv) * (VF / 4) + c] =
            make_float4(t.x + u.x, t.y + u.y, t.z + u.z, t.w + u.w);
    }
    if (tid == 0) dpart[bv * NSEG + seg] = sd[0] + sd[1] + sd[2] + sd[3];
}

__global__ __launch_bounds__(256) void out_kernel(const float4* __restrict__ Gpart,
                                                  const float* __restrict__ dpart,
                                                  float4* __restrict__ out) {
    int bv  = blockIdx.x >> 2;       // (b,v) pair
    int q   = blockIdx.x & 3;        // s-quarter: writes s in [q*8, q*8+8)
    int b   = bv >> 6;
    int v   = bv & 63;
    int tid = threadIdx.x;

    __shared__ float red[4];

    // denom: this b's 448 contiguous partials (dpart index = bv*7+seg), L2/L3-hot
    float val = dpart[b * NDP + tid];
    if (tid < NDP - 256) val += dpart[b * NDP + 256 + tid];
    #pragma unroll
    for (int off = 32; off > 0; off >>= 1) val += __shfl_xor(val, off, 64);
    if ((tid & 63) == 0) red[tid >> 6] = val;

    int c = tid & 127, half = tid >> 7;
    float4 gs = make_float4(0.f, 0.f, 0.f, 0.f);
    #pragma unroll
    for (int sgi = 0; sgi < NSEG; ++sgi) {
        float4 g = Gpart[((size_t)sgi * NBV + bv) * (VF / 4) + c];
        gs.x += g.x; gs.y += g.y; gs.z += g.z; gs.w += g.w;
    }
    __syncthreads();

    float inv = 1.0f / (red[0] + red[1] + red[2] + red[3]);
    float4 res = make_float4(gs.x * inv, gs.y * inv, gs.z * inv, gs.w * inv);

    #pragma unroll
    for (int k = 0; k < 4; k++) {
        int s = q * 8 + half * 4 + k;
        out[(((size_t)(b * ST + s)) * SV + v) * (VF / 4) + c] = res;
    }
}

extern "C" void kernel_launch(void* const* d_in, const int* in_sizes, int n_in,
                              void* d_out, int out_size, void* d_ws, size_t ws_size,
                              hipStream_t stream) {
    // inputs: 0=text (unused — softmax shift-invariance), 1=video,
    //         2=w (only w[512:] used), 3=b (unused)
    const float* video = (const float*)d_in[1];
    const float* w     = (const float*)d_in[2];
    float4* Gpart = (float4*)d_ws;                                   // 7*256*128*16B = 3.5 MiB
    float*  dpart = (float*)((char*)d_ws +
                             (size_t)NSEG * NBV * (VF / 4) * sizeof(float4));

    // PROBE FIRST (R4 only): 12-pass phase-A replica in production-A's cold
    // slot -> dur = coldA + ~50 us -> guaranteed top-5 row with FETCH_SIZE.
    // Its (12x-scaled) Gpart/dpart are overwritten by production A below.
    score_acc_kernel<12><<<dim3(NSEG, NBV), 256, 0, stream>>>((const float4*)video, w,
                                                              Gpart, dpart);

    // production pipeline (identical to R2; phase A now runs L3-warm)
    score_acc_kernel<1><<<dim3(NSEG, NBV), 256, 0, stream>>>((const float4*)video, w,
                                                             Gpart, dpart);
    out_kernel<<<NBV * 4, 256, 0, stream>>>(Gpart, dpart, (float4*)d_out);
}

// Round 7
// 163.986 us; speedup vs baseline: 1.1903x; 1.1903x over previous
//
#include <hip/hip_runtime.h>

#define TF 512
#define VF 512
#define BB 4
#define ST 32
#define SV 64
#define HW 196
#define NBV (BB * SV)       // 256 (b,v) pairs
#define NSEG 7              // h-segments per (b,v) -> 7 blocks/CU, SEGH=28 = 7 rows/wave exact
#define SEGH (HW / NSEG)    // 28
#define NDP (SV * NSEG)     // 448 denom partials per b

// Math: softmax over (v,h) is invariant to the additive per-(b,t) text score,
// so weights are t-independent and out[b,s,v,f] = G[b,v,f]/denom[b] for all 32 s.
//
// Measured decomposition (R1/R3/R4 probes, OH = 2x392MB harness re-poison
// fills ~117-120 us inside the timed window):
//   dur 164 = 120 fills + ~34 coldA + ~13 B
//   coldA: 50 MB video re-fetch (fills evicted it) at ~1.5 TB/s, sharing
//     HBM with the fills' L3 writeback drain. Same code warm: 2.5-4.5 us.
//     NOT latency/occupancy-bound (falsified R2: +75% occ = -2.4 us).
//   HBM-byte ledger models the whole window at ~160-172 us -> saturated;
//   only removing bytes helps.
//
// R7 = R5/R6 experiment, compile-fixed: __builtin_nontemporal_store rejects
// HIP_vector_type float4 (class, not clang vector) -> go through a native
// ext_vector_type(4) float alias; same 16B payload, emits
// global_store_dwordx4 ... nt. NT on `out` only: single-writer, never
// re-read -> skip RFO/allocate (~17 MB fetch saved) and don't dirty L3
// with 17 MB that would join the next re-poison drain. Gpart/dpart writes
// stay cached (B re-reads them).

typedef float nvec4 __attribute__((ext_vector_type(4)));

__device__ __forceinline__ void nt_store4(float4* p, float4 v) {
    nvec4 nv;
    nv.x = v.x; nv.y = v.y; nv.z = v.z; nv.w = v.w;
    __builtin_nontemporal_store(nv, reinterpret_cast<nvec4*>(p));
}

__global__ __launch_bounds__(256) void score_acc_kernel(const float4* __restrict__ video,
                                                        const float* __restrict__ w,
                                                        float4* __restrict__ Gpart,
                                                        float* __restrict__ dpart) {
    int seg  = blockIdx.x;          // 0..6
    int bv   = blockIdx.y;          // 0..255
    int tid  = threadIdx.x;
    int wave = tid >> 6;
    int lane = tid & 63;

    const float4* wv4 = (const float4*)(w + TF);
    float4 w0 = wv4[lane];
    float4 w1 = wv4[lane + 64];

    // wave handles rows {wave, wave+4, ...}: 7 rows each, no tail
    const float4* row = video + ((size_t)bv * HW + seg * SEGH + wave) * (VF / 4);
    float4 x0 = row[lane];
    float4 x1 = row[lane + 64];

    float4 acc0 = make_float4(0.f, 0.f, 0.f, 0.f);
    float4 acc1 = make_float4(0.f, 0.f, 0.f, 0.f);
    float  esum = 0.f;

    #pragma unroll
    for (int it = 0; it < SEGH / 4; ++it) {       // 7 iterations
        const float4* nrow = row + 4 * (VF / 4);
        float4 n0 = x0, n1 = x1;                  // dead copies on last iter (DCE'd)
        if (it < SEGH / 4 - 1) {                  // prefetch next row before the
            n0 = nrow[lane];                      // serial shuffle chain
            n1 = nrow[lane + 64];
        }
        float s = x0.x * w0.x + x0.y * w0.y + x0.z * w0.z + x0.w * w0.w
                + x1.x * w1.x + x1.y * w1.y + x1.z * w1.z + x1.w * w1.w;
        #pragma unroll
        for (int off = 32; off > 0; off >>= 1)
            s += __shfl_xor(s, off, 64);
        float e = __expf(s);
        esum += e;                                // identical across lanes
        acc0.x = fmaf(e, x0.x, acc0.x);
        acc0.y = fmaf(e, x0.y, acc0.y);
        acc0.z = fmaf(e, x0.z, acc0.z);
        acc0.w = fmaf(e, x0.w, acc0.w);
        acc1.x = fmaf(e, x1.x, acc1.x);
        acc1.y = fmaf(e, x1.y, acc1.y);
        acc1.z = fmaf(e, x1.z, acc1.z);
        acc1.w = fmaf(e, x1.w, acc1.w);
        x0 = n0; x1 = n1; row = nrow;
    }

    __shared__ float4 sacc[4][VF / 4];
    __shared__ float  sd[4];
    sacc[wave][lane]      = acc0;
    sacc[wave][lane + 64] = acc1;
    if (lane == 0) sd[wave] = esum;
    __syncthreads();

    int c = tid & 127, half = tid >> 7;
    float4 a  = sacc[half * 2][c];
    float4 bq = sacc[half * 2 + 1][c];
    float4 t  = make_float4(a.x + bq.x, a.y + bq.y, a.z + bq.z, a.w + bq.w);
    sacc[half * 2][c] = t;
    __syncthreads();
    if (half == 0) {
        float4 u = sacc[2][c];
        Gpart[((size_t)seg * NBV + bv) * (VF / 4) + c] =
            make_float4(t.x + u.x, t.y + u.y, t.z + u.z, t.w + u.w);
    }
    if (tid == 0) dpart[bv * NSEG + seg] = sd[0] + sd[1] + sd[2] + sd[3];
}

__global__ __launch_bounds__(256) void out_kernel(const float4* __restrict__ Gpart,
                                                  const float* __restrict__ dpart,
                                                  float4* __restrict__ out) {
    int bv  = blockIdx.x >> 2;       // (b,v) pair
    int q   = blockIdx.x & 3;        // s-quarter: writes s in [q*8, q*8+8)
    int b   = bv >> 6;
    int v   = bv & 63;
    int tid = threadIdx.x;

    __shared__ float red[4];

    // denom: this b's 448 contiguous partials (dpart index = bv*7+seg), L2/L3-hot
    float val = dpart[b * NDP + tid];
    if (tid < NDP - 256) val += dpart[b * NDP + 256 + tid];
    #pragma unroll
    for (int off = 32; off > 0; off >>= 1) val += __shfl_xor(val, off, 64);
    if ((tid & 63) == 0) red[tid >> 6] = val;

    int c = tid & 127, half = tid >> 7;
    float4 gs = make_float4(0.f, 0.f, 0.f, 0.f);
    #pragma unroll
    for (int sgi = 0; sgi < NSEG; ++sgi) {
        float4 g = Gpart[((size_t)sgi * NBV + bv) * (VF / 4) + c];
        gs.x += g.x; gs.y += g.y; gs.z += g.z; gs.w += g.w;
    }
    __syncthreads();

    float inv = 1.0f / (red[0] + red[1] + red[2] + red[3]);
    float4 res = make_float4(gs.x * inv, gs.y * inv, gs.z * inv, gs.w * inv);

    // Non-temporal: single-writer, never re-read by us -> no RFO/allocate,
    // and out's 17 MB doesn't dirty L3 (won't join the next re-poison drain).
    #pragma unroll
    for (int k = 0; k < 4; k++) {
        int s = q * 8 + half * 4 + k;
        nt_store4(&out[(((size_t)(b * ST + s)) * SV + v) * (VF / 4) + c], res);
    }
}

extern "C" void kernel_launch(void* const* d_in, const int* in_sizes, int n_in,
                              void* d_out, int out_size, void* d_ws, size_t ws_size,
                              hipStream_t stream) {
    // inputs: 0=text (unused — softmax shift-invariance), 1=video,
    //         2=w (only w[512:] used), 3=b (unused)
    const float* video = (const float*)d_in[1];
    const float* w     = (const float*)d_in[2];
    float4* Gpart = (float4*)d_ws;                                   // 7*256*128*16B = 3.5 MiB
    float*  dpart = (float*)((char*)d_ws +
                             (size_t)NSEG * NBV * (VF / 4) * sizeof(float4));

    score_acc_kernel<<<dim3(NSEG, NBV), 256, 0, stream>>>((const float4*)video, w,
                                                          Gpart, dpart);
    out_kernel<<<NBV * 4, 256, 0, stream>>>(Gpart, dpart, (float4*)d_out);
}